// Round 1
// baseline (162.381 us; speedup 1.0000x reference)
//
#include <hip/hip_runtime.h>
#include <math.h>

#define NB   2
#define H0   64
#define W0   64
#define NC   256
#define NPTS 4096
#define NLVL 4
#define NK   49   // (2*3+1)^2

__device__ __forceinline__ float wave_reduce_sum(float v) {
    for (int m = 32; m >= 1; m >>= 1)
        v += __shfl_xor(v, m, 64);
    return v;
}

__device__ __forceinline__ float wave_reduce_max(float v) {
    for (int m = 32; m >= 1; m >>= 1)
        v = fmaxf(v, __shfl_xor(v, m, 64));
    return v;
}

// packed signed-int8 dot4 with int32 accumulate
__device__ __forceinline__ int dot4i(unsigned a, unsigned b, int c) {
#if defined(__has_builtin)
#if __has_builtin(__builtin_amdgcn_sdot4)
    return __builtin_amdgcn_sdot4((int)a, (int)b, c, false);
#else
    c += (((int)(a << 24)) >> 24) * (((int)(b << 24)) >> 24);
    c += (((int)(a << 16)) >> 24) * (((int)(b << 16)) >> 24);
    c += (((int)(a <<  8)) >> 24) * (((int)(b <<  8)) >> 24);
    c += (((int)a) >> 24)         * (((int)b) >> 24);
    return c;
#endif
#else
    c += (((int)(a << 24)) >> 24) * (((int)(b << 24)) >> 24);
    c += (((int)(a << 16)) >> 24) * (((int)(b << 16)) >> 24);
    c += (((int)(a <<  8)) >> 24) * (((int)(b <<  8)) >> 24);
    c += (((int)a) >> 24)         * (((int)b) >> 24);
    return c;
#endif
}

// Quantize a wave-held unit vector (4 comps/lane) to int8 with per-vector
// symmetric scale; store packed dword/lane + scale. dot = (int32) * sa * sb.
__device__ __forceinline__ void quant_store(float nx, float ny, float nz, float nw,
                                            unsigned char* __restrict__ qout,
                                            size_t pixIdx,
                                            float* __restrict__ sout, int lane) {
    float m = fmaxf(fmaxf(fabsf(nx), fabsf(ny)), fmaxf(fabsf(nz), fabsf(nw)));
    float M = wave_reduce_max(m);
    float s = (M > 0.f) ? 127.f / M : 0.f;
    int qx = __float2int_rn(nx * s), qy = __float2int_rn(ny * s);
    int qz = __float2int_rn(nz * s), qw = __float2int_rn(nw * s);
    unsigned p = (qx & 0xff) | ((qy & 0xff) << 8) | ((qz & 0xff) << 16) | ((qw & 0xff) << 24);
    ((unsigned*)(qout + pixIdx * NC))[lane] = p;
    if (lane == 0) sout[pixIdx] = (M > 0.f) ? M / 127.f : 0.f;
}

// jax.image.resize bilinear antialias 2x downsample: separable [1,3,3,1]/8,
// OOB taps dropped + renormalized at edges. One wave per OUTPUT pixel.
// (level-1 only now; no raw output — levels 2/3 use composed filters.)
__device__ __forceinline__ void down_norm(const float* __restrict__ in,
                                          unsigned char* __restrict__ qout,
                                          float* __restrict__ sout,
                                          int Hi, int Wi, int wid, int lane) {
    int Ho = Hi >> 1, Wo = Wi >> 1;
    int b = wid / (Ho * Wo);
    int rem = wid - b * (Ho * Wo);
    int yo = rem / Wo, xo = rem - yo * Wo;
    float wy[4], wx[4]; int ty[4], tx[4];
    float sy = 0.f, sx = 0.f;
    for (int j = 0; j < 4; ++j) {
        float w = (j == 0 || j == 3) ? 1.f : 3.f;
        int yi = 2 * yo - 1 + j;
        float wyj = (yi >= 0 && yi < Hi) ? w : 0.f;
        ty[j] = min(max(yi, 0), Hi - 1); wy[j] = wyj; sy += wyj;
        int xi = 2 * xo - 1 + j;
        float wxj = (xi >= 0 && xi < Wi) ? w : 0.f;
        tx[j] = min(max(xi, 0), Wi - 1); wx[j] = wxj; sx += wxj;
    }
    float inv_s = 1.f / (sy * sx);
    float ax = 0.f, ay = 0.f, az = 0.f, aw = 0.f;
    const float4* basep = (const float4*)(in + (size_t)b * Hi * Wi * NC);
    for (int jy = 0; jy < 4; ++jy) {
        if (wy[jy] == 0.f) continue;
        for (int jx = 0; jx < 4; ++jx) {
            float w = wy[jy] * wx[jx];
            if (w == 0.f) continue;
            float4 v = basep[(ty[jy] * Wi + tx[jx]) * (NC / 4) + lane];
            ax += w * v.x; ay += w * v.y; az += w * v.z; aw += w * v.w;
        }
    }
    ax *= inv_s; ay *= inv_s; az *= inv_s; aw *= inv_s;
    float ss = wave_reduce_sum(ax * ax + ay * ay + az * az + aw * aw);
    float inv = 1.f / (sqrtf(ss) + 1e-6f);
    size_t po = (size_t)b * Ho * Wo + (size_t)yo * Wo + xo;
    quant_store(ax * inv, ay * inv, az * inv, aw * inv, qout, po, sout, lane);
}

// Compose `nst` cascaded [1,3,3,1]-with-edge-renorm 2x downsample stages into
// one tap set at the full 64 resolution (per axis). Output index o lives at
// res 64>>nst. Identical math to the cascade (each stage drops OOB taps and
// renormalizes by the in-bounds sum). nst=2 -> <=10 taps, nst=3 -> <=22 taps.
__device__ void compose_axis(int o, int nst, float* W, int* pb0, int* pn) {
    float a[22];
    int ba = o, na = 1, ra = 64 >> nst;
    a[0] = 1.f;
    for (int s = 0; s < nst; ++s) {
        float bt[22];
        int rb = ra << 1;
        int bb = 2 * ba - 1;
        int nb = 2 * na + 2;
        for (int k = 0; k < nb; ++k) bt[k] = 0.f;
        for (int k = 0; k < na; ++k) {
            float ak = a[k];
            if (ak == 0.f) continue;
            int j  = ba + k;
            int i0 = 2 * j - 1;
            float w0 = (i0     >= 0 && i0     < rb) ? 1.f : 0.f;
            float w1 = (i0 + 1 >= 0 && i0 + 1 < rb) ? 3.f : 0.f;
            float w2 = (i0 + 2 >= 0 && i0 + 2 < rb) ? 3.f : 0.f;
            float w3 = (i0 + 3 >= 0 && i0 + 3 < rb) ? 1.f : 0.f;
            float inv = ak / (w0 + w1 + w2 + w3);
            int off = i0 - bb;   // = 2*k, always in [0, nb-4]
            bt[off]     += w0 * inv;
            bt[off + 1] += w1 * inv;
            bt[off + 2] += w2 * inv;
            bt[off + 3] += w3 * inv;
        }
        ba = bb; na = nb; ra = rb;
        for (int k = 0; k < na; ++k) a[k] = bt[k];
    }
    *pb0 = ba; *pn = na;
    for (int k = 0; k < na; ++k) W[k] = a[k];
}

// Fused pyramid build (single launch, no internal dependencies):
//  [0,2048)     feat1 = normalize(bilinear(fmap1, coords1)) -> int8+scale
//  [2048,4096)  level-0 normalize -> int8+scale
//  [4096,4608)  level-1 downsample from fmap2 (one wave/pixel)
//  [4608,5120)  level-2: composed 10x10 taps from fmap2, one BLOCK/pixel
//  [5120,5248)  level-3: composed 22x22 taps from fmap2, one BLOCK/pixel
__global__ __launch_bounds__(256)
void build_kernel(const float* __restrict__ fmap1,
                  const float* __restrict__ fmap2,
                  const float* __restrict__ coords1,
                  unsigned char* __restrict__ f1q, float* __restrict__ fsc,
                  unsigned char* __restrict__ q0,  float* __restrict__ s0,
                  unsigned char* __restrict__ q1,  float* __restrict__ s1,
                  unsigned char* __restrict__ q2,  float* __restrict__ s2,
                  unsigned char* __restrict__ q3,  float* __restrict__ s3) {
    __shared__ float4 part[4][64];
    int blk  = blockIdx.x;
    int wv   = threadIdx.x >> 6;
    int lane = threadIdx.x & 63;
    if (blk < 2048) {
        int pt = blk * 4 + wv;
        int b = pt / NPTS;
        float x = coords1[pt * 2 + 0];
        float y = coords1[pt * 2 + 1];
        int x0 = min(max((int)floorf(x), 0), W0 - 1);
        int y0 = min(max((int)floorf(y), 0), H0 - 1);
        int x1 = min(x0 + 1, W0 - 1);
        int y1 = min(y0 + 1, H0 - 1);
        float wxh = x - (float)x0, wxl = (float)x1 - x;   // clip-first semantics
        float wyh = y - (float)y0, wyl = (float)y1 - y;
        float wa = wxl * wyl, wb = wxl * wyh, wc = wxh * wyl, wd = wxh * wyh;
        const float4* base = (const float4*)(fmap1 + (size_t)b * H0 * W0 * NC);
        float4 Ia = base[(y0 * W0 + x0) * (NC / 4) + lane];
        float4 Ib = base[(y1 * W0 + x0) * (NC / 4) + lane];
        float4 Ic = base[(y0 * W0 + x1) * (NC / 4) + lane];
        float4 Id = base[(y1 * W0 + x1) * (NC / 4) + lane];
        float vx = wa * Ia.x + wb * Ib.x + wc * Ic.x + wd * Id.x;
        float vy = wa * Ia.y + wb * Ib.y + wc * Ic.y + wd * Id.y;
        float vz = wa * Ia.z + wb * Ib.z + wc * Ic.z + wd * Id.z;
        float vw = wa * Ia.w + wb * Ib.w + wc * Ic.w + wd * Id.w;
        float ss = wave_reduce_sum(vx * vx + vy * vy + vz * vz + vw * vw);
        float inv = 1.0f / (sqrtf(ss) + 1e-6f);
        quant_store(vx * inv, vy * inv, vz * inv, vw * inv, f1q, pt, fsc, lane);
    } else if (blk < 4096) {
        int p = (blk - 2048) * 4 + wv;
        float4 v = ((const float4*)fmap2)[(size_t)p * (NC / 4) + lane];
        float ss = wave_reduce_sum(v.x * v.x + v.y * v.y + v.z * v.z + v.w * v.w);
        float inv = 1.0f / (sqrtf(ss) + 1e-6f);
        quant_store(v.x * inv, v.y * inv, v.z * inv, v.w * inv, q0, p, s0, lane);
    } else if (blk < 4608) {
        int wid = (blk - 4096) * 4 + wv;
        down_norm(fmap2, q1, s1, H0, W0, wid, lane);
    } else {
        // levels 2 and 3 directly from fmap2 via composed filters.
        int id = blk - 4608;
        int b, yo, xo, nst;
        unsigned char* qout; float* sout; size_t po;
        if (id < 512) {         // level 2: 2 x 16 x 16
            nst = 2;
            b = id >> 8; int rem = id & 255; yo = rem >> 4; xo = rem & 15;
            qout = q2; sout = s2; po = (size_t)b * 256 + yo * 16 + xo;
        } else {                // level 3: 2 x 8 x 8
            int id3 = id - 512;
            nst = 3;
            b = id3 >> 6; int rem = id3 & 63; yo = rem >> 3; xo = rem & 7;
            qout = q3; sout = s3; po = (size_t)b * 64 + yo * 8 + xo;
        }
        float Wy[22], Wx[22];
        int by, bx, ny, nx;
        compose_axis(yo, nst, Wy, &by, &ny);
        compose_axis(xo, nst, Wx, &bx, &nx);
        const float4* basep = (const float4*)(fmap2 + (size_t)b * H0 * W0 * NC);
        float ax = 0.f, ay = 0.f, az = 0.f, aw = 0.f;
        for (int ky = wv; ky < ny; ky += 4) {     // waves split tap rows
            float wyk = Wy[ky];
            if (wyk == 0.f) continue;
            int yi = by + ky;
            for (int kx = 0; kx < nx; ++kx) {
                float wxk = Wx[kx];
                if (wxk == 0.f) continue;
                float w = wyk * wxk;
                float4 v = basep[(yi * W0 + bx + kx) * (NC / 4) + lane];
                ax += w * v.x; ay += w * v.y; az += w * v.z; aw += w * v.w;
            }
        }
        float4 pr; pr.x = ax; pr.y = ay; pr.z = az; pr.w = aw;
        part[wv][lane] = pr;
        __syncthreads();
        if (wv == 0) {
            float4 p0 = part[0][lane], p1 = part[1][lane];
            float4 p2 = part[2][lane], p3 = part[3][lane];
            ax = p0.x + p1.x + p2.x + p3.x;
            ay = p0.y + p1.y + p2.y + p3.y;
            az = p0.z + p1.z + p2.z + p3.z;
            aw = p0.w + p1.w + p2.w + p3.w;
            float ss = wave_reduce_sum(ax * ax + ay * ay + az * az + aw * aw);
            float inv = 1.f / (sqrtf(ss) + 1e-6f);
            quant_store(ax * inv, ay * inv, az * inv, aw * inv, qout, po, sout, lane);
        }
    }
}

__device__ __forceinline__ int tile_dot(const uint4* buf, const uint4* a4) {
    int ac = 0;
#pragma unroll
    for (int s = 0; s < 4; ++s) {
        uint4 u = buf[s], av = a4[s];
        ac = dot4i(av.x, u.x, ac);
        ac = dot4i(av.y, u.y, ac);
        ac = dot4i(av.z, u.z, ac);
        ac = dot4i(av.w, u.w, ac);
    }
    return ac;
}

// One block per point, wave w = level. int8 pyramid, FULL 4-tile up-front
// prefetch. NOTE: Ds rows are wave-private (wave w writes AND reads only
// Ds[w]) -> no __syncthreads needed; the 4 waves run fully decoupled.
__global__ __launch_bounds__(256)
void corr_kernel(const unsigned char* __restrict__ f1q,
                 const float* __restrict__ fsc,
                 const float* __restrict__ coords2,
                 const unsigned char* __restrict__ q0, const float* __restrict__ s0,
                 const unsigned char* __restrict__ q1, const float* __restrict__ s1,
                 const unsigned char* __restrict__ q2, const float* __restrict__ s2,
                 const unsigned char* __restrict__ q3, const float* __restrict__ s3,
                 float* __restrict__ out) {
    __shared__ float Ds[NLVL][64];
    int pt = blockIdx.x;
    int b  = pt / NPTS;
    int t  = threadIdx.x;

    int w    = t >> 6;        // level
    int lane = t & 63;
    int Wl = W0 >> w, Hl = H0 >> w;
    float invs = 1.0f / (float)(1 << w);
    float cx = coords2[pt * 2 + 0] * invs;
    float cy = coords2[pt * 2 + 1] * invs;
    int ix = (int)floorf(cx), iy = (int)floorf(cy);

    const unsigned char* f2q = (w == 0) ? q0 : (w == 1) ? q1 : (w == 2) ? q2 : q3;
    const float*         f2s = (w == 0) ? s0 : (w == 1) ? s1 : (w == 2) ? s2 : s3;

    int cg = lane & 3;        // channel chunk group
    int pq = lane >> 2;       // pixel slot (0..15)

    const uint4* pixp[4];
    int pidx[4];
#pragma unroll
    for (int i = 0; i < 4; ++i) {
        int p  = i * 16 + pq;            // grid pixel 0..63
        int jx = p & 7, jy = p >> 3;
        int px = min(max(ix - 3 + jx, 0), Wl - 1);
        int py = min(max(iy - 3 + jy, 0), Hl - 1);
        pidx[i] = (b * Hl + py) * Wl + px;
        pixp[i] = (const uint4*)(f2q + (size_t)pidx[i] * NC);
    }

    // ---- issue ALL loads up front ----
    uint4 bufs[4][4];
#pragma unroll
    for (int i = 0; i < 4; ++i)
#pragma unroll
        for (int s = 0; s < 4; ++s)
            bufs[i][s] = pixp[i][s * 4 + cg];

    const uint4* f1p = (const uint4*)(f1q + (size_t)pt * NC);
    uint4 a4[4];
#pragma unroll
    for (int s = 0; s < 4; ++s) a4[s] = f1p[s * 4 + cg];

    float sb[4];
#pragma unroll
    for (int i = 0; i < 4; ++i) sb[i] = f2s[pidx[i]];
    float sa = fsc[pt];

    // ---- 4 independent dot chains ----
#pragma unroll
    for (int i = 0; i < 4; ++i) {
        int r = tile_dot(bufs[i], a4);
        r += __shfl_xor(r, 1, 64);
        r += __shfl_xor(r, 2, 64);
        if (cg == 0) Ds[w][i * 16 + pq] = (float)r * sa * sb[i];
    }
    // no __syncthreads(): Ds[w] is produced and consumed by wave w only.

    if (lane < NK) {
        int tyk = lane / 7, txk = lane % 7;
        float dx = (float)(txk - 3), dy = (float)(tyk - 3);
        float x = fminf(fmaxf(cx + dx, 0.f), (float)(Wl - 1));
        float y = fminf(fmaxf(cy + dy, 0.f), (float)(Hl - 1));
        int x0 = (int)floorf(x);
        int y0 = (int)floorf(y);
        int x1 = min(x0 + 1, Wl - 1);
        int y1 = min(y0 + 1, Hl - 1);
        float wxh = x - (float)x0, wxl = (float)x1 - x;  // both 0 at exact upper edge
        float wyh = y - (float)y0, wyl = (float)y1 - y;
        int sx0 = min(max(x0 - ix + 3, 0), 7);
        int sx1 = min(max(x1 - ix + 3, 0), 7);
        int sy0 = min(max(y0 - iy + 3, 0), 7);
        int sy1 = min(max(y1 - iy + 3, 0), 7);
        float v = wxl * wyl * Ds[w][sy0 * 8 + sx0]
                + wxl * wyh * Ds[w][sy1 * 8 + sx0]
                + wxh * wyl * Ds[w][sy0 * 8 + sx1]
                + wxh * wyh * Ds[w][sy1 * 8 + sx1];
        out[(size_t)pt * (NLVL * NK) + w * NK + lane] = v;
    }
}

extern "C" void kernel_launch(void* const* d_in, const int* in_sizes, int n_in,
                              void* d_out, int out_size, void* d_ws, size_t ws_size,
                              hipStream_t stream) {
    const float* fmap1   = (const float*)d_in[0];
    const float* fmap2   = (const float*)d_in[1];
    const float* coords1 = (const float*)d_in[2];
    const float* coords2 = (const float*)d_in[3];
    float* out = (float*)d_out;
    float* ws  = (float*)d_ws;

    // workspace layout (float-slot offsets, all multiples of 4 -> 16B aligned)
    // raw1 eliminated (levels 2/3 are composed directly from fmap2).
    unsigned char* f1q = (unsigned char*)ws;                 // 2,097,152 B
    float*         fsc = ws + 524288;                        // 8,192 floats
    unsigned char* q0  = (unsigned char*)(ws + 532480);      // 2,097,152 B
    float*         s0  = ws + 1056768;                       // 8,192 floats
    unsigned char* q1  = (unsigned char*)(ws + 1064960);     // 524,288 B
    float*         s1  = ws + 1196032;                       // 2,048 floats
    unsigned char* q2  = (unsigned char*)(ws + 1198080);     // 131,072 B
    float*         s2  = ws + 1230848;                       // 512 floats
    unsigned char* q3  = (unsigned char*)(ws + 1231360);     // 32,768 B
    float*         s3  = ws + 1239552;                       // 128 floats
    // total ~1,239,680 float slots = 4.96 MiB

    build_kernel<<<5248, 256, 0, stream>>>(fmap1, fmap2, coords1,
                                           f1q, fsc, q0, s0, q1, s1,
                                           q2, s2, q3, s3);
    corr_kernel<<<NB * NPTS, 256, 0, stream>>>(f1q, fsc, coords2,
                                               q0, s0, q1, s1, q2, s2, q3, s3, out);
}

// Round 2
// 109.882 us; speedup vs baseline: 1.4778x; 1.4778x over previous
//
#include <hip/hip_runtime.h>
#include <math.h>

#define NB   2
#define H0   64
#define W0   64
#define NC   256
#define NPTS 4096
#define NLVL 4
#define NK   49   // (2*3+1)^2

__device__ __forceinline__ float wave_reduce_sum(float v) {
    for (int m = 32; m >= 1; m >>= 1)
        v += __shfl_xor(v, m, 64);
    return v;
}

__device__ __forceinline__ float wave_reduce_max(float v) {
    for (int m = 32; m >= 1; m >>= 1)
        v = fmaxf(v, __shfl_xor(v, m, 64));
    return v;
}

// packed signed-int8 dot4 with int32 accumulate
__device__ __forceinline__ int dot4i(unsigned a, unsigned b, int c) {
#if defined(__has_builtin)
#if __has_builtin(__builtin_amdgcn_sdot4)
    return __builtin_amdgcn_sdot4((int)a, (int)b, c, false);
#else
    c += (((int)(a << 24)) >> 24) * (((int)(b << 24)) >> 24);
    c += (((int)(a << 16)) >> 24) * (((int)(b << 16)) >> 24);
    c += (((int)(a <<  8)) >> 24) * (((int)(b <<  8)) >> 24);
    c += (((int)a) >> 24)         * (((int)b) >> 24);
    return c;
#endif
#else
    c += (((int)(a << 24)) >> 24) * (((int)(b << 24)) >> 24);
    c += (((int)(a << 16)) >> 24) * (((int)(b << 16)) >> 24);
    c += (((int)(a <<  8)) >> 24) * (((int)(b <<  8)) >> 24);
    c += (((int)a) >> 24)         * (((int)b) >> 24);
    return c;
#endif
}

// Quantize a wave-held unit vector (4 comps/lane) to int8 with per-vector
// symmetric scale; store packed dword/lane + scale. dot = (int32) * sa * sb.
__device__ __forceinline__ void quant_store(float nx, float ny, float nz, float nw,
                                            unsigned char* __restrict__ qout,
                                            size_t pixIdx,
                                            float* __restrict__ sout, int lane) {
    float m = fmaxf(fmaxf(fabsf(nx), fabsf(ny)), fmaxf(fabsf(nz), fabsf(nw)));
    float M = wave_reduce_max(m);
    float s = (M > 0.f) ? 127.f / M : 0.f;
    int qx = __float2int_rn(nx * s), qy = __float2int_rn(ny * s);
    int qz = __float2int_rn(nz * s), qw = __float2int_rn(nw * s);
    unsigned p = (qx & 0xff) | ((qy & 0xff) << 8) | ((qz & 0xff) << 16) | ((qw & 0xff) << 24);
    ((unsigned*)(qout + pixIdx * NC))[lane] = p;
    if (lane == 0) sout[pixIdx] = (M > 0.f) ? M / 127.f : 0.f;
}

// jax.image.resize bilinear antialias 2x downsample: separable [1,3,3,1]/8,
// OOB taps dropped + renormalized at edges. One wave per OUTPUT pixel.
__device__ __forceinline__ void down_norm(const float* __restrict__ in,
                                          float* __restrict__ raw_out,
                                          unsigned char* __restrict__ qout,
                                          float* __restrict__ sout,
                                          int Hi, int Wi, int wid, int lane) {
    int Ho = Hi >> 1, Wo = Wi >> 1;
    int b = wid / (Ho * Wo);
    int rem = wid - b * (Ho * Wo);
    int yo = rem / Wo, xo = rem - yo * Wo;
    float wy[4], wx[4]; int ty[4], tx[4];
    float sy = 0.f, sx = 0.f;
    for (int j = 0; j < 4; ++j) {
        float w = (j == 0 || j == 3) ? 1.f : 3.f;
        int yi = 2 * yo - 1 + j;
        float wyj = (yi >= 0 && yi < Hi) ? w : 0.f;
        ty[j] = min(max(yi, 0), Hi - 1); wy[j] = wyj; sy += wyj;
        int xi = 2 * xo - 1 + j;
        float wxj = (xi >= 0 && xi < Wi) ? w : 0.f;
        tx[j] = min(max(xi, 0), Wi - 1); wx[j] = wxj; sx += wxj;
    }
    float inv_s = 1.f / (sy * sx);
    float ax = 0.f, ay = 0.f, az = 0.f, aw = 0.f;
    const float4* basep = (const float4*)(in + (size_t)b * Hi * Wi * NC);
    for (int jy = 0; jy < 4; ++jy) {
        if (wy[jy] == 0.f) continue;
        for (int jx = 0; jx < 4; ++jx) {
            float w = wy[jy] * wx[jx];
            if (w == 0.f) continue;
            float4 v = basep[(ty[jy] * Wi + tx[jx]) * (NC / 4) + lane];
            ax += w * v.x; ay += w * v.y; az += w * v.z; aw += w * v.w;
        }
    }
    ax *= inv_s; ay *= inv_s; az *= inv_s; aw *= inv_s;
    float ss = wave_reduce_sum(ax * ax + ay * ay + az * az + aw * aw);
    float inv = 1.f / (sqrtf(ss) + 1e-6f);
    size_t po = (size_t)b * Ho * Wo + (size_t)yo * Wo + xo;
    if (raw_out) {
        float4 r; r.x = ax; r.y = ay; r.z = az; r.w = aw;
        ((float4*)raw_out)[po * (NC / 4) + lane] = r;
    }
    quant_store(ax * inv, ay * inv, az * inv, aw * inv, qout, po, sout, lane);
}

// Fused preprocessing (streaming):
//  [0,2048)    feat1 = normalize(bilinear(fmap1, coords1)) -> int8+scale
//  [2048,4096) level-0 normalize -> int8+scale
//  [4096,4608) level-1 downsample (raw fp32 + int8 norm)
__global__ __launch_bounds__(256)
void pre_kernel(const float* __restrict__ fmap1,
                const float* __restrict__ fmap2,
                const float* __restrict__ coords1,
                unsigned char* __restrict__ f1q, float* __restrict__ fsc,
                unsigned char* __restrict__ q0,  float* __restrict__ s0,
                float* __restrict__ raw1,
                unsigned char* __restrict__ q1,  float* __restrict__ s1) {
    int blk  = blockIdx.x;
    int wv   = threadIdx.x >> 6;
    int lane = threadIdx.x & 63;
    if (blk < 2048) {
        int pt = blk * 4 + wv;
        int b = pt / NPTS;
        float x = coords1[pt * 2 + 0];
        float y = coords1[pt * 2 + 1];
        int x0 = min(max((int)floorf(x), 0), W0 - 1);
        int y0 = min(max((int)floorf(y), 0), H0 - 1);
        int x1 = min(x0 + 1, W0 - 1);
        int y1 = min(y0 + 1, H0 - 1);
        float wxh = x - (float)x0, wxl = (float)x1 - x;   // clip-first semantics
        float wyh = y - (float)y0, wyl = (float)y1 - y;
        float wa = wxl * wyl, wb = wxl * wyh, wc = wxh * wyl, wd = wxh * wyh;
        const float4* base = (const float4*)(fmap1 + (size_t)b * H0 * W0 * NC);
        float4 Ia = base[(y0 * W0 + x0) * (NC / 4) + lane];
        float4 Ib = base[(y1 * W0 + x0) * (NC / 4) + lane];
        float4 Ic = base[(y0 * W0 + x1) * (NC / 4) + lane];
        float4 Id = base[(y1 * W0 + x1) * (NC / 4) + lane];
        float vx = wa * Ia.x + wb * Ib.x + wc * Ic.x + wd * Id.x;
        float vy = wa * Ia.y + wb * Ib.y + wc * Ic.y + wd * Id.y;
        float vz = wa * Ia.z + wb * Ib.z + wc * Ic.z + wd * Id.z;
        float vw = wa * Ia.w + wb * Ib.w + wc * Ic.w + wd * Id.w;
        float ss = wave_reduce_sum(vx * vx + vy * vy + vz * vz + vw * vw);
        float inv = 1.0f / (sqrtf(ss) + 1e-6f);
        quant_store(vx * inv, vy * inv, vz * inv, vw * inv, f1q, pt, fsc, lane);
    } else if (blk < 4096) {
        int p = (blk - 2048) * 4 + wv;
        float4 v = ((const float4*)fmap2)[(size_t)p * (NC / 4) + lane];
        float ss = wave_reduce_sum(v.x * v.x + v.y * v.y + v.z * v.z + v.w * v.w);
        float inv = 1.0f / (sqrtf(ss) + 1e-6f);
        quant_store(v.x * inv, v.y * inv, v.z * inv, v.w * inv, q0, p, s0, lane);
    } else {
        int wid = (blk - 4096) * 4 + wv;
        down_norm(fmap2, raw1, q1, s1, H0, W0, wid, lane);
    }
}

// Small levels from raw1 (cascade), one BLOCK per output pixel.
//  [0,512)   level2: 4x4 taps from raw1 (32x32), wave wv takes row jy==wv
//  [512,640) level3: composed 10x10 taps from raw1, wave wv takes ky%4==wv
__global__ __launch_bounds__(256)
void small_kernel(const float* __restrict__ raw1,
                  unsigned char* __restrict__ q2, float* __restrict__ s2,
                  unsigned char* __restrict__ q3, float* __restrict__ s3) {
    __shared__ float4 part[4][64];
    int blk  = blockIdx.x;
    int wv   = threadIdx.x >> 6;
    int lane = threadIdx.x & 63;
    float ax = 0.f, ay = 0.f, az = 0.f, aw = 0.f;
    unsigned char* qout; float* sout; size_t po;

    if (blk < 512) {
        // level 2: output grid 2x16x16 from raw1 (32x32)
        int b = blk >> 8, rem = blk & 255;
        int yo = rem >> 4, xo = rem & 15;
        float wy[4], wx[4]; int ty[4], tx[4];
        float sy = 0.f, sx = 0.f;
#pragma unroll
        for (int j = 0; j < 4; ++j) {
            float w = (j == 0 || j == 3) ? 1.f : 3.f;
            int yi = 2 * yo - 1 + j;
            float wyj = (yi >= 0 && yi < 32) ? w : 0.f;
            ty[j] = min(max(yi, 0), 31); wy[j] = wyj; sy += wyj;
            int xi = 2 * xo - 1 + j;
            float wxj = (xi >= 0 && xi < 32) ? w : 0.f;
            tx[j] = min(max(xi, 0), 31); wx[j] = wxj; sx += wxj;
        }
        float inv_s = 1.f / (sy * sx);
        const float4* basep = (const float4*)(raw1 + (size_t)b * 32 * 32 * NC);
        int jy = wv;
        if (wy[jy] != 0.f) {
#pragma unroll
            for (int jx = 0; jx < 4; ++jx) {
                float w = wy[jy] * wx[jx] * inv_s;
                if (wx[jx] == 0.f) continue;
                float4 v = basep[(ty[jy] * 32 + tx[jx]) * (NC / 4) + lane];
                ax += w * v.x; ay += w * v.y; az += w * v.z; aw += w * v.w;
            }
        }
        qout = q2; sout = s2; po = (size_t)b * 256 + yo * 16 + xo;
    } else {
        // level 3: output grid 2x8x8, composed 10-tap filter from raw1 (32x32)
        int wid = blk - 512;
        int b = wid >> 6, rem = wid & 63;
        int yo = rem >> 3, xo = rem & 7;
        float Wt[2][10]; int base[2];
        for (int d = 0; d < 2; ++d) {
            int o = d ? xo : yo;
            base[d] = 4 * o - 3;
            float W[10];
            for (int k = 0; k < 10; ++k) W[k] = 0.f;
            float S2 = 0.f;
            for (int j = 0; j < 4; ++j) {
                int yj = 2 * o - 1 + j;
                if (yj < 0 || yj >= 16) continue;
                float wj = (j == 0 || j == 3) ? 1.f : 3.f;
                S2 += wj;
                int yi0 = 2 * yj - 1;
                float wi[4], s1v = 0.f;
                for (int i2 = 0; i2 < 4; ++i2) {
                    int yi = yi0 + i2;
                    wi[i2] = (yi >= 0 && yi < 32) ? ((i2 == 0 || i2 == 3) ? 1.f : 3.f) : 0.f;
                    s1v += wi[i2];
                }
                float sc = wj / s1v;
                for (int i2 = 0; i2 < 4; ++i2)
                    if (wi[i2] > 0.f) W[yi0 + i2 - base[d]] += wi[i2] * sc;
            }
            float invS = 1.f / S2;
            for (int k = 0; k < 10; ++k) Wt[d][k] = W[k] * invS;
        }
        const float4* basep = (const float4*)(raw1 + (size_t)b * 32 * 32 * NC);
        for (int ky = wv; ky < 10; ky += 4) {
            float wyk = Wt[0][ky];
            if (wyk == 0.f) continue;
            int yi = base[0] + ky;
#pragma unroll
            for (int kx = 0; kx < 10; ++kx) {
                float wxk = Wt[1][kx];
                if (wxk == 0.f) continue;
                int xi = base[1] + kx;
                float wgt = wyk * wxk;
                float4 v = basep[(yi * 32 + xi) * (NC / 4) + lane];
                ax += wgt * v.x; ay += wgt * v.y; az += wgt * v.z; aw += wgt * v.w;
            }
        }
        qout = q3; sout = s3; po = (size_t)b * 64 + yo * 8 + xo;
    }

    float4 pr; pr.x = ax; pr.y = ay; pr.z = az; pr.w = aw;
    part[wv][lane] = pr;
    __syncthreads();
    if (wv == 0) {
        float4 p0 = part[0][lane], p1 = part[1][lane];
        float4 p2 = part[2][lane], p3 = part[3][lane];
        ax = p0.x + p1.x + p2.x + p3.x;
        ay = p0.y + p1.y + p2.y + p3.y;
        az = p0.z + p1.z + p2.z + p3.z;
        aw = p0.w + p1.w + p2.w + p3.w;
        float ss = wave_reduce_sum(ax * ax + ay * ay + az * az + aw * aw);
        float inv = 1.f / (sqrtf(ss) + 1e-6f);
        quant_store(ax * inv, ay * inv, az * inv, aw * inv, qout, po, sout, lane);
    }
}

__device__ __forceinline__ int tile_dot(const uint4* buf, const uint4* a4) {
    int ac = 0;
#pragma unroll
    for (int s = 0; s < 4; ++s) {
        uint4 u = buf[s], av = a4[s];
        ac = dot4i(av.x, u.x, ac);
        ac = dot4i(av.y, u.y, ac);
        ac = dot4i(av.z, u.z, ac);
        ac = dot4i(av.w, u.w, ac);
    }
    return ac;
}

// One block per point, wave w = level. int8 pyramid, FULL 4-tile up-front
// prefetch. NOTE: Ds rows are wave-private (wave w writes AND reads only
// Ds[w]) -> no __syncthreads needed; the 4 waves run fully decoupled.
// (HW-verified correct in R1: passed with identical absmax.)
__global__ __launch_bounds__(256)
void corr_kernel(const unsigned char* __restrict__ f1q,
                 const float* __restrict__ fsc,
                 const float* __restrict__ coords2,
                 const unsigned char* __restrict__ q0, const float* __restrict__ s0,
                 const unsigned char* __restrict__ q1, const float* __restrict__ s1,
                 const unsigned char* __restrict__ q2, const float* __restrict__ s2,
                 const unsigned char* __restrict__ q3, const float* __restrict__ s3,
                 float* __restrict__ out) {
    __shared__ float Ds[NLVL][64];
    int pt = blockIdx.x;
    int b  = pt / NPTS;
    int t  = threadIdx.x;

    int w    = t >> 6;        // level
    int lane = t & 63;
    int Wl = W0 >> w, Hl = H0 >> w;
    float invs = 1.0f / (float)(1 << w);
    float cx = coords2[pt * 2 + 0] * invs;
    float cy = coords2[pt * 2 + 1] * invs;
    int ix = (int)floorf(cx), iy = (int)floorf(cy);

    const unsigned char* f2q = (w == 0) ? q0 : (w == 1) ? q1 : (w == 2) ? q2 : q3;
    const float*         f2s = (w == 0) ? s0 : (w == 1) ? s1 : (w == 2) ? s2 : s3;

    int cg = lane & 3;        // channel chunk group
    int pq = lane >> 2;       // pixel slot (0..15)

    const uint4* pixp[4];
    int pidx[4];
#pragma unroll
    for (int i = 0; i < 4; ++i) {
        int p  = i * 16 + pq;            // grid pixel 0..63
        int jx = p & 7, jy = p >> 3;
        int px = min(max(ix - 3 + jx, 0), Wl - 1);
        int py = min(max(iy - 3 + jy, 0), Hl - 1);
        pidx[i] = (b * Hl + py) * Wl + px;
        pixp[i] = (const uint4*)(f2q + (size_t)pidx[i] * NC);
    }

    // ---- issue ALL loads up front ----
    uint4 bufs[4][4];
#pragma unroll
    for (int i = 0; i < 4; ++i)
#pragma unroll
        for (int s = 0; s < 4; ++s)
            bufs[i][s] = pixp[i][s * 4 + cg];

    const uint4* f1p = (const uint4*)(f1q + (size_t)pt * NC);
    uint4 a4[4];
#pragma unroll
    for (int s = 0; s < 4; ++s) a4[s] = f1p[s * 4 + cg];

    float sb[4];
#pragma unroll
    for (int i = 0; i < 4; ++i) sb[i] = f2s[pidx[i]];
    float sa = fsc[pt];

    // ---- 4 independent dot chains ----
#pragma unroll
    for (int i = 0; i < 4; ++i) {
        int r = tile_dot(bufs[i], a4);
        r += __shfl_xor(r, 1, 64);
        r += __shfl_xor(r, 2, 64);
        if (cg == 0) Ds[w][i * 16 + pq] = (float)r * sa * sb[i];
    }
    // no __syncthreads(): Ds[w] is produced and consumed by wave w only.

    if (lane < NK) {
        int tyk = lane / 7, txk = lane % 7;
        float dx = (float)(txk - 3), dy = (float)(tyk - 3);
        float x = fminf(fmaxf(cx + dx, 0.f), (float)(Wl - 1));
        float y = fminf(fmaxf(cy + dy, 0.f), (float)(Hl - 1));
        int x0 = (int)floorf(x);
        int y0 = (int)floorf(y);
        int x1 = min(x0 + 1, Wl - 1);
        int y1 = min(y0 + 1, Hl - 1);
        float wxh = x - (float)x0, wxl = (float)x1 - x;  // both 0 at exact upper edge
        float wyh = y - (float)y0, wyl = (float)y1 - y;
        int sx0 = min(max(x0 - ix + 3, 0), 7);
        int sx1 = min(max(x1 - ix + 3, 0), 7);
        int sy0 = min(max(y0 - iy + 3, 0), 7);
        int sy1 = min(max(y1 - iy + 3, 0), 7);
        float v = wxl * wyl * Ds[w][sy0 * 8 + sx0]
                + wxl * wyh * Ds[w][sy1 * 8 + sx0]
                + wxh * wyl * Ds[w][sy0 * 8 + sx1]
                + wxh * wyh * Ds[w][sy1 * 8 + sx1];
        out[(size_t)pt * (NLVL * NK) + w * NK + lane] = v;
    }
}

extern "C" void kernel_launch(void* const* d_in, const int* in_sizes, int n_in,
                              void* d_out, int out_size, void* d_ws, size_t ws_size,
                              hipStream_t stream) {
    const float* fmap1   = (const float*)d_in[0];
    const float* fmap2   = (const float*)d_in[1];
    const float* coords1 = (const float*)d_in[2];
    const float* coords2 = (const float*)d_in[3];
    float* out = (float*)d_out;
    float* ws  = (float*)d_ws;

    // workspace layout (float-slot offsets, all multiples of 4 -> 16B aligned)
    float*         raw1 = ws;                               // 524,288 floats
    unsigned char* f1q  = (unsigned char*)(ws + 524288);    // 2,097,152 B
    float*         fsc  = ws + 1048576;                     // 8,192 floats
    unsigned char* q0   = (unsigned char*)(ws + 1056768);   // 2,097,152 B
    float*         s0   = ws + 1581056;                     // 8,192 floats
    unsigned char* q1   = (unsigned char*)(ws + 1589248);   // 524,288 B
    float*         s1   = ws + 1720320;                     // 2,048 floats
    unsigned char* q2   = (unsigned char*)(ws + 1722368);   // 131,072 B
    float*         s2   = ws + 1755136;                     // 512 floats
    unsigned char* q3   = (unsigned char*)(ws + 1755648);   // 32,768 B
    float*         s3   = ws + 1763840;                     // 128 floats
    // total ~1,764,000 float slots = 6.7 MiB

    pre_kernel<<<4608, 256, 0, stream>>>(fmap1, fmap2, coords1,
                                         f1q, fsc, q0, s0, raw1, q1, s1);
    small_kernel<<<640, 256, 0, stream>>>(raw1, q2, s2, q3, s3);
    corr_kernel<<<NB * NPTS, 256, 0, stream>>>(f1q, fsc, coords2,
                                               q0, s0, q1, s1, q2, s2, q3, s3, out);
}

// Round 3
// 107.766 us; speedup vs baseline: 1.5068x; 1.0196x over previous
//
#include <hip/hip_runtime.h>
#include <math.h>

#define NB   2
#define H0   64
#define W0   64
#define NC   256
#define NPTS 4096
#define NLVL 4
#define NK   49   // (2*3+1)^2

__device__ __forceinline__ float wave_reduce_sum(float v) {
    for (int m = 32; m >= 1; m >>= 1)
        v += __shfl_xor(v, m, 64);
    return v;
}

__device__ __forceinline__ float wave_reduce_max(float v) {
    for (int m = 32; m >= 1; m >>= 1)
        v = fmaxf(v, __shfl_xor(v, m, 64));
    return v;
}

// packed signed-int8 dot4 with int32 accumulate
__device__ __forceinline__ int dot4i(unsigned a, unsigned b, int c) {
#if defined(__has_builtin)
#if __has_builtin(__builtin_amdgcn_sdot4)
    return __builtin_amdgcn_sdot4((int)a, (int)b, c, false);
#else
    c += (((int)(a << 24)) >> 24) * (((int)(b << 24)) >> 24);
    c += (((int)(a << 16)) >> 24) * (((int)(b << 16)) >> 24);
    c += (((int)(a <<  8)) >> 24) * (((int)(b <<  8)) >> 24);
    c += (((int)a) >> 24)         * (((int)b) >> 24);
    return c;
#endif
#else
    c += (((int)(a << 24)) >> 24) * (((int)(b << 24)) >> 24);
    c += (((int)(a << 16)) >> 24) * (((int)(b << 16)) >> 24);
    c += (((int)(a <<  8)) >> 24) * (((int)(b <<  8)) >> 24);
    c += (((int)a) >> 24)         * (((int)b) >> 24);
    return c;
#endif
}

// Composed 2-stage [1,3,3,1]/8-with-edge-renorm filter, 32-res -> 8-res.
// Row o: taps at i = 4*o-3+k, k=0..9. Interior rows = [1,3,6,10,12,12,10,6,3,1]/64.
// o=0 / o=7 rows hand-composed with per-stage OOB-drop + renorm (sum to 1).
// Zeros mark OOB taps (guarded by weight==0 skip before address calc).
__constant__ float L3W[8][10] = {
    {0.f, 0.f, 0.f, 0.18367347f, 0.23724490f, 0.22193878f,
     0.17857143f, 0.10714286f, 0.05357143f, 0.01785714f},
    {0.015625f, 0.046875f, 0.09375f, 0.15625f, 0.1875f, 0.1875f,
     0.15625f, 0.09375f, 0.046875f, 0.015625f},
    {0.015625f, 0.046875f, 0.09375f, 0.15625f, 0.1875f, 0.1875f,
     0.15625f, 0.09375f, 0.046875f, 0.015625f},
    {0.015625f, 0.046875f, 0.09375f, 0.15625f, 0.1875f, 0.1875f,
     0.15625f, 0.09375f, 0.046875f, 0.015625f},
    {0.015625f, 0.046875f, 0.09375f, 0.15625f, 0.1875f, 0.1875f,
     0.15625f, 0.09375f, 0.046875f, 0.015625f},
    {0.015625f, 0.046875f, 0.09375f, 0.15625f, 0.1875f, 0.1875f,
     0.15625f, 0.09375f, 0.046875f, 0.015625f},
    {0.015625f, 0.046875f, 0.09375f, 0.15625f, 0.1875f, 0.1875f,
     0.15625f, 0.09375f, 0.046875f, 0.015625f},
    {0.01785714f, 0.05357143f, 0.10714286f, 0.17857143f, 0.22193878f,
     0.23724490f, 0.18367347f, 0.f, 0.f, 0.f}
};

// Quantize a wave-held unit vector (4 comps/lane) to int8 with per-vector
// symmetric scale; store packed dword/lane + scale. dot = (int32) * sa * sb.
__device__ __forceinline__ void quant_store(float nx, float ny, float nz, float nw,
                                            unsigned char* __restrict__ qout,
                                            size_t pixIdx,
                                            float* __restrict__ sout, int lane) {
    float m = fmaxf(fmaxf(fabsf(nx), fabsf(ny)), fmaxf(fabsf(nz), fabsf(nw)));
    float M = wave_reduce_max(m);
    float s = (M > 0.f) ? 127.f / M : 0.f;
    int qx = __float2int_rn(nx * s), qy = __float2int_rn(ny * s);
    int qz = __float2int_rn(nz * s), qw = __float2int_rn(nw * s);
    unsigned p = (qx & 0xff) | ((qy & 0xff) << 8) | ((qz & 0xff) << 16) | ((qw & 0xff) << 24);
    ((unsigned*)(qout + pixIdx * NC))[lane] = p;
    if (lane == 0) sout[pixIdx] = (M > 0.f) ? M / 127.f : 0.f;
}

// jax.image.resize bilinear antialias 2x downsample: separable [1,3,3,1]/8,
// OOB taps dropped + renormalized at edges. One wave per OUTPUT pixel.
__device__ __forceinline__ void down_norm(const float* __restrict__ in,
                                          float* __restrict__ raw_out,
                                          unsigned char* __restrict__ qout,
                                          float* __restrict__ sout,
                                          int Hi, int Wi, int wid, int lane) {
    int Ho = Hi >> 1, Wo = Wi >> 1;
    int b = wid / (Ho * Wo);
    int rem = wid - b * (Ho * Wo);
    int yo = rem / Wo, xo = rem - yo * Wo;
    float wy[4], wx[4]; int ty[4], tx[4];
    float sy = 0.f, sx = 0.f;
#pragma unroll
    for (int j = 0; j < 4; ++j) {
        float w = (j == 0 || j == 3) ? 1.f : 3.f;
        int yi = 2 * yo - 1 + j;
        float wyj = (yi >= 0 && yi < Hi) ? w : 0.f;
        ty[j] = min(max(yi, 0), Hi - 1); wy[j] = wyj; sy += wyj;
        int xi = 2 * xo - 1 + j;
        float wxj = (xi >= 0 && xi < Wi) ? w : 0.f;
        tx[j] = min(max(xi, 0), Wi - 1); wx[j] = wxj; sx += wxj;
    }
    float inv_s = 1.f / (sy * sx);
    float ax = 0.f, ay = 0.f, az = 0.f, aw = 0.f;
    const float4* basep = (const float4*)(in + (size_t)b * Hi * Wi * NC);
#pragma unroll
    for (int jy = 0; jy < 4; ++jy) {
        if (wy[jy] == 0.f) continue;
#pragma unroll
        for (int jx = 0; jx < 4; ++jx) {
            float w = wy[jy] * wx[jx];
            if (w == 0.f) continue;
            float4 v = basep[(ty[jy] * Wi + tx[jx]) * (NC / 4) + lane];
            ax += w * v.x; ay += w * v.y; az += w * v.z; aw += w * v.w;
        }
    }
    ax *= inv_s; ay *= inv_s; az *= inv_s; aw *= inv_s;
    float ss = wave_reduce_sum(ax * ax + ay * ay + az * az + aw * aw);
    float inv = 1.f / (sqrtf(ss) + 1e-6f);
    size_t po = (size_t)b * Ho * Wo + (size_t)yo * Wo + xo;
    if (raw_out) {
        float4 r; r.x = ax; r.y = ay; r.z = az; r.w = aw;
        ((float4*)raw_out)[po * (NC / 4) + lane] = r;
    }
    quant_store(ax * inv, ay * inv, az * inv, aw * inv, qout, po, sout, lane);
}

// Fused preprocessing (streaming), HEAVY BLOCKS FIRST so light blocks fill
// the dispatch tail:
//  [0,512)     level-1 downsample (raw fp32 + int8 norm)  -- 16 loads/lane
//  [512,2560)  feat1 = normalize(bilinear(fmap1, coords1)) -- 4 loads/lane
//  [2560,4608) level-0 normalize                           -- 1 load/lane
__global__ __launch_bounds__(256)
void pre_kernel(const float* __restrict__ fmap1,
                const float* __restrict__ fmap2,
                const float* __restrict__ coords1,
                unsigned char* __restrict__ f1q, float* __restrict__ fsc,
                unsigned char* __restrict__ q0,  float* __restrict__ s0,
                float* __restrict__ raw1,
                unsigned char* __restrict__ q1,  float* __restrict__ s1) {
    int blk  = blockIdx.x;
    int wv   = threadIdx.x >> 6;
    int lane = threadIdx.x & 63;
    if (blk < 512) {
        int wid = blk * 4 + wv;
        down_norm(fmap2, raw1, q1, s1, H0, W0, wid, lane);
    } else if (blk < 2560) {
        int pt = (blk - 512) * 4 + wv;
        int b = pt / NPTS;
        float x = coords1[pt * 2 + 0];
        float y = coords1[pt * 2 + 1];
        int x0 = min(max((int)floorf(x), 0), W0 - 1);
        int y0 = min(max((int)floorf(y), 0), H0 - 1);
        int x1 = min(x0 + 1, W0 - 1);
        int y1 = min(y0 + 1, H0 - 1);
        float wxh = x - (float)x0, wxl = (float)x1 - x;   // clip-first semantics
        float wyh = y - (float)y0, wyl = (float)y1 - y;
        float wa = wxl * wyl, wb = wxl * wyh, wc = wxh * wyl, wd = wxh * wyh;
        const float4* base = (const float4*)(fmap1 + (size_t)b * H0 * W0 * NC);
        float4 Ia = base[(y0 * W0 + x0) * (NC / 4) + lane];
        float4 Ib = base[(y1 * W0 + x0) * (NC / 4) + lane];
        float4 Ic = base[(y0 * W0 + x1) * (NC / 4) + lane];
        float4 Id = base[(y1 * W0 + x1) * (NC / 4) + lane];
        float vx = wa * Ia.x + wb * Ib.x + wc * Ic.x + wd * Id.x;
        float vy = wa * Ia.y + wb * Ib.y + wc * Ic.y + wd * Id.y;
        float vz = wa * Ia.z + wb * Ib.z + wc * Ic.z + wd * Id.z;
        float vw = wa * Ia.w + wb * Ib.w + wc * Ic.w + wd * Id.w;
        float ss = wave_reduce_sum(vx * vx + vy * vy + vz * vz + vw * vw);
        float inv = 1.0f / (sqrtf(ss) + 1e-6f);
        quant_store(vx * inv, vy * inv, vz * inv, vw * inv, f1q, pt, fsc, lane);
    } else {
        int p = (blk - 2560) * 4 + wv;
        float4 v = ((const float4*)fmap2)[(size_t)p * (NC / 4) + lane];
        float ss = wave_reduce_sum(v.x * v.x + v.y * v.y + v.z * v.z + v.w * v.w);
        float inv = 1.0f / (sqrtf(ss) + 1e-6f);
        quant_store(v.x * inv, v.y * inv, v.z * inv, v.w * inv, q0, p, s0, lane);
    }
}

// Small levels from raw1 (cascade), one BLOCK per output pixel.
// SCRATCH-FREE rewrite: level-2 weights in closed form (no runtime-indexed
// stack arrays); level-3 weights from the __constant__ composed table.
//  [0,512)   level2: 4x4 taps from raw1 (32x32), wave wv takes tap-row wv
//  [512,640) level3: composed 10x10 taps from raw1, wave wv takes ky%4==wv
__global__ __launch_bounds__(256)
void small_kernel(const float* __restrict__ raw1,
                  unsigned char* __restrict__ q2, float* __restrict__ s2,
                  unsigned char* __restrict__ q3, float* __restrict__ s3) {
    __shared__ float4 part[4][64];
    int blk  = blockIdx.x;
    int wv   = threadIdx.x >> 6;
    int lane = threadIdx.x & 63;
    float ax = 0.f, ay = 0.f, az = 0.f, aw = 0.f;
    unsigned char* qout; float* sout; size_t po;

    if (blk < 512) {
        // level 2: output grid 2x16x16 from raw1 (32x32)
        int b = blk >> 8, rem = blk & 255;
        int yo = rem >> 4, xo = rem & 15;
        // OOB only at yo==0 (tap j=0 -> yi=-1) and yo==15 (tap j=3 -> yi=32)
        float sy = 8.f - (yo == 0 ? 1.f : 0.f) - (yo == 15 ? 1.f : 0.f);
        float sx = 8.f - (xo == 0 ? 1.f : 0.f) - (xo == 15 ? 1.f : 0.f);
        float inv_s = 1.f / (sy * sx);
        const float4* basep = (const float4*)(raw1 + (size_t)b * 32 * 32 * NC);
        int yi = 2 * yo - 1 + wv;
        float wyj = (wv == 0 || wv == 3) ? 1.f : 3.f;
        if (yi >= 0 && yi < 32) {
#pragma unroll
            for (int jx = 0; jx < 4; ++jx) {
                int xi = 2 * xo - 1 + jx;
                if (xi < 0 || xi >= 32) continue;
                float w = wyj * ((jx == 0 || jx == 3) ? 1.f : 3.f) * inv_s;
                float4 v = basep[(yi * 32 + xi) * (NC / 4) + lane];
                ax += w * v.x; ay += w * v.y; az += w * v.z; aw += w * v.w;
            }
        }
        qout = q2; sout = s2; po = (size_t)b * 256 + yo * 16 + xo;
    } else {
        // level 3: output grid 2x8x8, composed 10-tap filter from raw1 (32x32)
        int wid = blk - 512;
        int b = wid >> 6, rem = wid & 63;
        int yo = rem >> 3, xo = rem & 7;
        const float* wyrow = L3W[yo];
        const float* wxrow = L3W[xo];
        int ybase = 4 * yo - 3, xbase = 4 * xo - 3;
        const float4* basep = (const float4*)(raw1 + (size_t)b * 32 * 32 * NC);
        for (int ky = wv; ky < 10; ky += 4) {
            float wyk = wyrow[ky];
            if (wyk == 0.f) continue;        // guards OOB taps too
            int yi = ybase + ky;
#pragma unroll
            for (int kx = 0; kx < 10; ++kx) {
                float wxk = wxrow[kx];
                if (wxk == 0.f) continue;
                int xi = xbase + kx;
                float w = wyk * wxk;
                float4 v = basep[(yi * 32 + xi) * (NC / 4) + lane];
                ax += w * v.x; ay += w * v.y; az += w * v.z; aw += w * v.w;
            }
        }
        qout = q3; sout = s3; po = (size_t)b * 64 + yo * 8 + xo;
    }

    float4 pr; pr.x = ax; pr.y = ay; pr.z = az; pr.w = aw;
    part[wv][lane] = pr;
    __syncthreads();
    if (wv == 0) {
        float4 p0 = part[0][lane], p1 = part[1][lane];
        float4 p2 = part[2][lane], p3 = part[3][lane];
        ax = p0.x + p1.x + p2.x + p3.x;
        ay = p0.y + p1.y + p2.y + p3.y;
        az = p0.z + p1.z + p2.z + p3.z;
        aw = p0.w + p1.w + p2.w + p3.w;
        float ss = wave_reduce_sum(ax * ax + ay * ay + az * az + aw * aw);
        float inv = 1.f / (sqrtf(ss) + 1e-6f);
        quant_store(ax * inv, ay * inv, az * inv, aw * inv, qout, po, sout, lane);
    }
}

__device__ __forceinline__ int tile_dot(const uint4* buf, const uint4* a4) {
    int ac = 0;
#pragma unroll
    for (int s = 0; s < 4; ++s) {
        uint4 u = buf[s], av = a4[s];
        ac = dot4i(av.x, u.x, ac);
        ac = dot4i(av.y, u.y, ac);
        ac = dot4i(av.z, u.z, ac);
        ac = dot4i(av.w, u.w, ac);
    }
    return ac;
}

// One block per point, wave w = level. int8 pyramid, FULL 4-tile up-front
// prefetch. Ds rows are wave-private -> no __syncthreads (verified R1/R2).
__global__ __launch_bounds__(256)
void corr_kernel(const unsigned char* __restrict__ f1q,
                 const float* __restrict__ fsc,
                 const float* __restrict__ coords2,
                 const unsigned char* __restrict__ q0, const float* __restrict__ s0,
                 const unsigned char* __restrict__ q1, const float* __restrict__ s1,
                 const unsigned char* __restrict__ q2, const float* __restrict__ s2,
                 const unsigned char* __restrict__ q3, const float* __restrict__ s3,
                 float* __restrict__ out) {
    __shared__ float Ds[NLVL][64];
    int pt = blockIdx.x;
    int b  = pt / NPTS;
    int t  = threadIdx.x;

    int w    = t >> 6;        // level
    int lane = t & 63;
    int Wl = W0 >> w, Hl = H0 >> w;
    float invs = 1.0f / (float)(1 << w);
    float cx = coords2[pt * 2 + 0] * invs;
    float cy = coords2[pt * 2 + 1] * invs;
    int ix = (int)floorf(cx), iy = (int)floorf(cy);

    const unsigned char* f2q = (w == 0) ? q0 : (w == 1) ? q1 : (w == 2) ? q2 : q3;
    const float*         f2s = (w == 0) ? s0 : (w == 1) ? s1 : (w == 2) ? s2 : s3;

    int cg = lane & 3;        // channel chunk group
    int pq = lane >> 2;       // pixel slot (0..15)

    const uint4* pixp[4];
    int pidx[4];
#pragma unroll
    for (int i = 0; i < 4; ++i) {
        int p  = i * 16 + pq;            // grid pixel 0..63
        int jx = p & 7, jy = p >> 3;
        int px = min(max(ix - 3 + jx, 0), Wl - 1);
        int py = min(max(iy - 3 + jy, 0), Hl - 1);
        pidx[i] = (b * Hl + py) * Wl + px;
        pixp[i] = (const uint4*)(f2q + (size_t)pidx[i] * NC);
    }

    // ---- issue ALL loads up front ----
    uint4 bufs[4][4];
#pragma unroll
    for (int i = 0; i < 4; ++i)
#pragma unroll
        for (int s = 0; s < 4; ++s)
            bufs[i][s] = pixp[i][s * 4 + cg];

    const uint4* f1p = (const uint4*)(f1q + (size_t)pt * NC);
    uint4 a4[4];
#pragma unroll
    for (int s = 0; s < 4; ++s) a4[s] = f1p[s * 4 + cg];

    float sb[4];
#pragma unroll
    for (int i = 0; i < 4; ++i) sb[i] = f2s[pidx[i]];
    float sa = fsc[pt];

    // ---- 4 independent dot chains ----
#pragma unroll
    for (int i = 0; i < 4; ++i) {
        int r = tile_dot(bufs[i], a4);
        r += __shfl_xor(r, 1, 64);
        r += __shfl_xor(r, 2, 64);
        if (cg == 0) Ds[w][i * 16 + pq] = (float)r * sa * sb[i];
    }

    if (lane < NK) {
        int tyk = lane / 7, txk = lane % 7;
        float dx = (float)(txk - 3), dy = (float)(tyk - 3);
        float x = fminf(fmaxf(cx + dx, 0.f), (float)(Wl - 1));
        float y = fminf(fmaxf(cy + dy, 0.f), (float)(Hl - 1));
        int x0 = (int)floorf(x);
        int y0 = (int)floorf(y);
        int x1 = min(x0 + 1, Wl - 1);
        int y1 = min(y0 + 1, Hl - 1);
        float wxh = x - (float)x0, wxl = (float)x1 - x;  // both 0 at exact upper edge
        float wyh = y - (float)y0, wyl = (float)y1 - y;
        int sx0 = min(max(x0 - ix + 3, 0), 7);
        int sx1 = min(max(x1 - ix + 3, 0), 7);
        int sy0 = min(max(y0 - iy + 3, 0), 7);
        int sy1 = min(max(y1 - iy + 3, 0), 7);
        float v = wxl * wyl * Ds[w][sy0 * 8 + sx0]
                + wxl * wyh * Ds[w][sy1 * 8 + sx0]
                + wxh * wyl * Ds[w][sy0 * 8 + sx1]
                + wxh * wyh * Ds[w][sy1 * 8 + sx1];
        out[(size_t)pt * (NLVL * NK) + w * NK + lane] = v;
    }
}

extern "C" void kernel_launch(void* const* d_in, const int* in_sizes, int n_in,
                              void* d_out, int out_size, void* d_ws, size_t ws_size,
                              hipStream_t stream) {
    const float* fmap1   = (const float*)d_in[0];
    const float* fmap2   = (const float*)d_in[1];
    const float* coords1 = (const float*)d_in[2];
    const float* coords2 = (const float*)d_in[3];
    float* out = (float*)d_out;
    float* ws  = (float*)d_ws;

    // workspace layout (float-slot offsets, all multiples of 4 -> 16B aligned)
    float*         raw1 = ws;                               // 524,288 floats
    unsigned char* f1q  = (unsigned char*)(ws + 524288);    // 2,097,152 B
    float*         fsc  = ws + 1048576;                     // 8,192 floats
    unsigned char* q0   = (unsigned char*)(ws + 1056768);   // 2,097,152 B
    float*         s0   = ws + 1581056;                     // 8,192 floats
    unsigned char* q1   = (unsigned char*)(ws + 1589248);   // 524,288 B
    float*         s1   = ws + 1720320;                     // 2,048 floats
    unsigned char* q2   = (unsigned char*)(ws + 1722368);   // 131,072 B
    float*         s2   = ws + 1755136;                     // 512 floats
    unsigned char* q3   = (unsigned char*)(ws + 1755648);   // 32,768 B
    float*         s3   = ws + 1763840;                     // 128 floats
    // total ~1,764,000 float slots = 6.7 MiB

    pre_kernel<<<4608, 256, 0, stream>>>(fmap1, fmap2, coords1,
                                         f1q, fsc, q0, s0, raw1, q1, s1);
    small_kernel<<<640, 256, 0, stream>>>(raw1, q2, s2, q3, s3);
    corr_kernel<<<NB * NPTS, 256, 0, stream>>>(f1q, fsc, coords2,
                                               q0, s0, q1, s1, q2, s2, q3, s3, out);
}